// Round 9
// baseline (559.321 us; speedup 1.0000x reference)
//
#include <hip/hip_runtime.h>
#include <hip/hip_bf16.h>
#include <stdint.h>

#define D_MODEL 1024
#define NHEADS  8
#define DKH     128
#define DFF     4096
#define SEQ     2048
#define BATCH   4
#define NTOK    (BATCH*SEQ)   // 8192
#define QKS     2048          // row stride of fused QK buffer
// 1/sqrt(128) * log2(e): folded into Q at the QKV GEMM (exp2-domain softmax)
#define QSCALE  0.12751743f

typedef float  f32x4  __attribute__((ext_vector_type(4)));
typedef __bf16 bf16x8 __attribute__((ext_vector_type(8)));

static __device__ __forceinline__ float b2f(ushort u) {
    union { uint32_t i; float f; } v; v.i = ((uint32_t)u) << 16; return v.f;
}
static __device__ __forceinline__ ushort f2b(float f) {
    union { float f; uint32_t i; } v; v.f = f;
    uint32_t r = v.i + 0x7fffu + ((v.i >> 16) & 1u);
    return (ushort)(r >> 16);
}
static __device__ __forceinline__ ushort f2b_native(float f) {
    __bf16 h = (__bf16)f;               // v_cvt (RTNE, same rounding as f2b)
    return __builtin_bit_cast(ushort, h);
}
// hardware 2^x (v_exp_f32)
static __device__ __forceinline__ float exp2_hw(float x) {
    return __builtin_amdgcn_exp2f(x);
}
static __device__ __forceinline__ void gl_lds16(const void* g, void* l) {
    __builtin_amdgcn_global_load_lds(
        (const __attribute__((address_space(1))) void*)g,
        (__attribute__((address_space(3))) void*)l, 16, 0, 0);
}
// butterfly max over each aligned 16-lane group via DPP (no LDS traffic)
static __device__ __forceinline__ float dpp_max16(float x) {
    int t;
    t = __builtin_amdgcn_update_dpp(0, __builtin_bit_cast(int, x), 0xB1, 0xF, 0xF, true);  // quad_perm [1,0,3,2] : xor1
    x = fmaxf(x, __builtin_bit_cast(float, t));
    t = __builtin_amdgcn_update_dpp(0, __builtin_bit_cast(int, x), 0x4E, 0xF, 0xF, true);  // quad_perm [2,3,0,1] : xor2
    x = fmaxf(x, __builtin_bit_cast(float, t));
    t = __builtin_amdgcn_update_dpp(0, __builtin_bit_cast(int, x), 0x141, 0xF, 0xF, true); // row_half_mirror : xor7
    x = fmaxf(x, __builtin_bit_cast(float, t));
    t = __builtin_amdgcn_update_dpp(0, __builtin_bit_cast(int, x), 0x140, 0xF, 0xF, true); // row_mirror : xor15
    x = fmaxf(x, __builtin_bit_cast(float, t));
    return x;
}

// ---------------------------------------------------------------------------
__global__ __launch_bounds__(256) void conv_kernel(
    const float* __restrict__ in, ushort* __restrict__ out, int n)
{
    for (int i = (blockIdx.x * 256 + threadIdx.x) * 4; i < n; i += gridDim.x * 1024) {
        float4 v = *(const float4*)(in + i);
        ushort o[4] = { f2b(v.x), f2b(v.y), f2b(v.z), f2b(v.w) };
        *(uint2*)(out + i) = *(const uint2*)o;
    }
}

// transpose + convert: fp32 [R][C] -> bf16 [C][R]
__global__ __launch_bounds__(256) void tconv_kernel(
    const float* __restrict__ in, ushort* __restrict__ out, int R, int C)
{
    __shared__ float L[32][33];
    const int tid = threadIdx.x;
    const int tx = tid & 31, ty = tid >> 5;
    const int nbc = C >> 5;
    const int r0 = (blockIdx.x / nbc) << 5;
    const int c0 = (blockIdx.x % nbc) << 5;
    #pragma unroll
    for (int p = 0; p < 4; ++p)
        L[ty + 8 * p][tx] = in[(size_t)(r0 + ty + 8 * p) * C + c0 + tx];
    __syncthreads();
    #pragma unroll
    for (int p = 0; p < 4; ++p)
        out[(size_t)(c0 + ty + 8 * p) * R + r0 + tx] = f2b(L[tx][ty + 8 * p]);
}

// fused transpose+convert of Wq|Wk|Wv (each 1024x1024) into wqkv_t
__global__ __launch_bounds__(256) void tconv3_kernel(
    const float* __restrict__ a, const float* __restrict__ b,
    const float* __restrict__ c, ushort* __restrict__ out)
{
    __shared__ float L[32][33];
    const int which = blockIdx.x >> 10;
    const float* in = (which == 0) ? a : (which == 1) ? b : c;
    ushort* o = out + (size_t)which * 1024 * 1024;
    const int bix = blockIdx.x & 1023;
    const int tid = threadIdx.x;
    const int tx = tid & 31, ty = tid >> 5;
    const int r0 = (bix >> 5) << 5;
    const int c0 = (bix & 31) << 5;
    #pragma unroll
    for (int p = 0; p < 4; ++p)
        L[ty + 8 * p][tx] = in[(size_t)(r0 + ty + 8 * p) * 1024 + c0 + tx];
    __syncthreads();
    #pragma unroll
    for (int p = 0; p < 4; ++p)
        o[(size_t)(c0 + ty + 8 * p) * 1024 + r0 + tx] = f2b(L[tx][ty + 8 * p]);
}

__global__ __launch_bounds__(256) void cat3_kernel(
    const float* __restrict__ a, const float* __restrict__ b,
    const float* __restrict__ c, float* __restrict__ out)
{
    const int i = blockIdx.x * 256 + threadIdx.x;
    out[i] = (i < 1024) ? a[i] : (i < 2048) ? b[i - 1024] : c[i - 2048];
}

// ---------------------------------------------------------------------------
// gemm8_relu: 256x256 tile, BK=64, 512 threads (8 waves 2M x 4N), deep
// pipeline with COUNTED vmcnt (T3+T4). C = relu(A @ Bt^T + bias), bf16.
// (verified round 4)
// ---------------------------------------------------------------------------
__global__ __launch_bounds__(512, 2) void gemm8_relu(
    const ushort* __restrict__ A, const ushort* __restrict__ Bt,
    const float* __restrict__ bias, ushort* __restrict__ C,
    int M, int N, int K)
{
    __shared__ __align__(16) ushort lds[65536];   // 128 KB

    const int tid  = threadIdx.x;
    const int w    = tid >> 6;          // 0..7
    const int lane = tid & 63;
    const int l16  = lane & 15;
    const int quad = (lane >> 4) & 3;
    const int wm   = w >> 2;            // 0..1 (M half)
    const int wn   = w & 3;             // 0..3 (N quarter)

    const int nbn = N >> 8;
    const int m0  = (blockIdx.x / nbn) << 8;
    const int n0  = (blockIdx.x % nbn) << 8;

    const int rsub = tid >> 3;                       // 0..63
    const int gsw  = (tid & 7) ^ (rsub & 7);         // pre-swizzled src group
    const ushort* Asrc = A  + (size_t)(m0 + rsub) * K + gsw * 8;
    const ushort* Bsrc = Bt + (size_t)(n0 + rsub) * K + gsw * 8;

    auto issue_half = [&](int p, int kt, int d) {
        const ushort* src;
        int base;
        if (p < 2) { src = Asrc + (size_t)(p * 128) * K;       base = d * 16384 + p * 8192; }
        else       { src = Bsrc + (size_t)((p - 2) * 128) * K; base = 32768 + d * 16384 + (p - 2) * 8192; }
        src += kt * 64;
        gl_lds16(src,                  &lds[base + w * 512]);
        gl_lds16(src + (size_t)64 * K, &lds[base + w * 512 + 4096]);
    };

    f32x4  acc[8][4] = {};
    bf16x8 bfr[4];

    auto phase = [&](int cur, int ks, int mq, bool readB) {
        const int Ab = cur * 16384 + wm * 8192;
        const int Bb = 32768 + cur * 16384 + (wn >> 1) * 8192;
        if (readB) {
            #pragma unroll
            for (int nt = 0; nt < 4; ++nt) {
                const int rB = ((wn & 1) << 6) + nt * 16 + l16;
                const int gB = ((ks << 2) + quad) ^ (rB & 7);
                bfr[nt] = *(const bf16x8*)&lds[Bb + rB * 64 + gB * 8];
            }
        }
        bf16x8 afr[4];
        #pragma unroll
        for (int mt = 0; mt < 4; ++mt) {
            const int rA = mq * 64 + mt * 16 + l16;
            const int gA = ((ks << 2) + quad) ^ (rA & 7);
            afr[mt] = *(const bf16x8*)&lds[Ab + rA * 64 + gA * 8];
        }
        __builtin_amdgcn_s_setprio(1);
        #pragma unroll
        for (int mt = 0; mt < 4; ++mt)
            #pragma unroll
            for (int nt = 0; nt < 4; ++nt)
                acc[mq * 4 + mt][nt] = __builtin_amdgcn_mfma_f32_16x16x32_bf16(
                    afr[mt], bfr[nt], acc[mq * 4 + mt][nt], 0, 0, 0);
        __builtin_amdgcn_s_setprio(0);
    };

    const int NT = K >> 6;

    #pragma unroll
    for (int p = 0; p < 4; ++p) issue_half(p, 0, 0);
    issue_half(0, 1, 1);
    asm volatile("s_waitcnt vmcnt(2)" ::: "memory");
    __builtin_amdgcn_sched_barrier(0);
    __builtin_amdgcn_s_barrier();
    __builtin_amdgcn_sched_barrier(0);

    for (int t = 0; t < NT; ++t) {
        const int  cur = t & 1;
        const bool pf  = (t + 1 < NT);

        if (pf) issue_half(1, t + 1, cur ^ 1);
        phase(cur, 0, 0, true);
        if (pf) issue_half(2, t + 1, cur ^ 1);
        phase(cur, 0, 1, false);
        if (pf) issue_half(3, t + 1, cur ^ 1);
        phase(cur, 1, 0, true);
        phase(cur, 1, 1, false);

        __builtin_amdgcn_sched_barrier(0);
        __builtin_amdgcn_s_barrier();          // A
        __builtin_amdgcn_sched_barrier(0);
        if (pf) {
            if (t + 2 < NT) {
                issue_half(0, t + 2, cur);
                asm volatile("s_waitcnt vmcnt(2)" ::: "memory");
            } else {
                asm volatile("s_waitcnt vmcnt(0)" ::: "memory");
            }
            __builtin_amdgcn_sched_barrier(0);
            __builtin_amdgcn_s_barrier();      // B
            __builtin_amdgcn_sched_barrier(0);
        }
    }
    __builtin_amdgcn_sched_barrier(0);

    #pragma unroll
    for (int nt = 0; nt < 4; ++nt) {
        const int n = n0 + wn * 64 + nt * 16 + l16;
        const float bv = bias[n];
        #pragma unroll
        for (int a = 0; a < 8; ++a) {
            const int mrow = m0 + wm * 128 + (a >> 2) * 64 + (a & 3) * 16 + (quad << 2);
            #pragma unroll
            for (int r = 0; r < 4; ++r) {
                const float v = fmaxf(acc[a][nt][r] + bv, 0.f);
                C[(size_t)(mrow + r) * N + n] = f2b(v);
            }
        }
    }
}

// ---------------------------------------------------------------------------
// gemm12: 128x256 tile, BK=64, 512 threads (8 waves 2M x 4N, wave = 64x64),
// counted-vmcnt deep pipeline, 96 KB LDS. (verified round 5)
// MODE 2: QKV epilogue; MODE 3: split-K 2 slices.
// ---------------------------------------------------------------------------
template<int MODE>
__global__ __launch_bounds__(512, 2) void gemm12(
    const ushort* __restrict__ A, const ushort* __restrict__ Bt,
    const float* __restrict__ bias, ushort* __restrict__ C,
    ushort* __restrict__ C2, int M, int N, int K)
{
    __shared__ __align__(16) ushort lds[49152];   // 96 KB

    const int tid  = threadIdx.x;
    const int w    = tid >> 6;
    const int lane = tid & 63;
    const int l16  = lane & 15;
    const int quad = (lane >> 4) & 3;
    const int wm   = w >> 2;
    const int wn   = w & 3;

    const int cpx  = gridDim.x >> 3;
    const int bidx = (blockIdx.x & 7) * cpx + (blockIdx.x >> 3);

    int tix = bidx, kbeg = 0, kend = K, sl = 0;
    if (MODE == 3) {
        const int tiles = (M >> 7) * (N >> 8);
        sl   = bidx / tiles;
        tix  = bidx % tiles;
        kbeg = sl * (K >> 1);
        kend = kbeg + (K >> 1);
    }
    const int nbn = N >> 8;
    const int m0  = (tix / nbn) << 7;
    const int n0  = (tix % nbn) << 8;

    const int rsub = tid >> 3;
    const int gsw  = (tid & 7) ^ (rsub & 7);
    const ushort* Asrc = A  + (size_t)(m0 + rsub) * K + gsw * 8 + kbeg;
    const ushort* Bsrc = Bt + (size_t)(n0 + rsub) * K + gsw * 8 + kbeg;

    auto issue_half = [&](int p, int kt, int d) {
        const ushort* src;
        int base;
        if (p == 0) { src = Asrc;                              base = d * 8192; }
        else        { src = Bsrc + (size_t)((p - 1) * 128) * K; base = 16384 + d * 16384 + (p - 1) * 8192; }
        src += kt * 64;
        gl_lds16(src,                  &lds[base + w * 512]);
        gl_lds16(src + (size_t)64 * K, &lds[base + w * 512 + 4096]);
    };

    f32x4 acc[4][4] = {};

    auto phase = [&](int cur, int ks) {
        const int Ab = cur * 8192;
        const int Bb = 16384 + cur * 16384;
        bf16x8 afr[4], bfr[4];
        #pragma unroll
        for (int nt = 0; nt < 4; ++nt) {
            const int rB = wn * 64 + nt * 16 + l16;
            const int gB = ((ks << 2) + quad) ^ (rB & 7);
            bfr[nt] = *(const bf16x8*)&lds[Bb + rB * 64 + gB * 8];
        }
        #pragma unroll
        for (int mt = 0; mt < 4; ++mt) {
            const int rA = wm * 64 + mt * 16 + l16;
            const int gA = ((ks << 2) + quad) ^ (rA & 7);
            afr[mt] = *(const bf16x8*)&lds[Ab + rA * 64 + gA * 8];
        }
        __builtin_amdgcn_s_setprio(1);
        #pragma unroll
        for (int mt = 0; mt < 4; ++mt)
            #pragma unroll
            for (int nt = 0; nt < 4; ++nt)
                acc[mt][nt] = __builtin_amdgcn_mfma_f32_16x16x32_bf16(
                    afr[mt], bfr[nt], acc[mt][nt], 0, 0, 0);
        __builtin_amdgcn_s_setprio(0);
    };

    const int NT = (kend - kbeg) >> 6;

    issue_half(0, 0, 0);
    issue_half(1, 0, 0);
    issue_half(2, 0, 0);
    issue_half(0, 1, 1);
    asm volatile("s_waitcnt vmcnt(2)" ::: "memory");
    __builtin_amdgcn_sched_barrier(0);
    __builtin_amdgcn_s_barrier();
    __builtin_amdgcn_sched_barrier(0);

    for (int t = 0; t < NT; ++t) {
        const int  cur = t & 1;
        const bool pf  = (t + 1 < NT);

        if (pf) issue_half(1, t + 1, cur ^ 1);
        phase(cur, 0);
        if (pf) issue_half(2, t + 1, cur ^ 1);
        phase(cur, 1);

        __builtin_amdgcn_sched_barrier(0);
        __builtin_amdgcn_s_barrier();          // A
        __builtin_amdgcn_sched_barrier(0);
        if (pf) {
            if (t + 2 < NT) {
                issue_half(0, t + 2, cur);
                asm volatile("s_waitcnt vmcnt(2)" ::: "memory");
            } else {
                asm volatile("s_waitcnt vmcnt(0)" ::: "memory");
            }
            __builtin_amdgcn_sched_barrier(0);
            __builtin_amdgcn_s_barrier();      // B
            __builtin_amdgcn_sched_barrier(0);
        }
    }
    __builtin_amdgcn_sched_barrier(0);

    if (MODE == 2 && n0 >= 2048) {
        #pragma unroll
        for (int nt = 0; nt < 4; ++nt) {
            const int n  = n0 + wn * 64 + nt * 16 + l16;
            const int hd = n - 2048;
            const float bv = bias[n];
            const size_t vrow = (size_t)(hd >> 7) * 128 + (hd & 127);
            #pragma unroll
            for (int mt = 0; mt < 4; ++mt) {
                const int m = m0 + wm * 64 + mt * 16 + (quad << 2);
                const size_t row = (size_t)(m >> 11) * 1024 + vrow;
                ushort pk[4];
                #pragma unroll
                for (int r = 0; r < 4; ++r) pk[r] = f2b(acc[mt][nt][r] + bv);
                *(uint2*)(C2 + row * SEQ + (m & 2047)) = *(const uint2*)pk;
            }
        }
    } else if (MODE == 2) {
        const float qs = (n0 < 1024) ? QSCALE : 1.f;
        #pragma unroll
        for (int nt = 0; nt < 4; ++nt) {
            const int n = n0 + wn * 64 + nt * 16 + l16;
            const float bv = bias[n];
            #pragma unroll
            for (int mt = 0; mt < 4; ++mt) {
                #pragma unroll
                for (int r = 0; r < 4; ++r) {
                    const int m = m0 + wm * 64 + mt * 16 + (quad << 2) + r;
                    C[(size_t)m * QKS + n] = f2b((acc[mt][nt][r] + bv) * qs);
                }
            }
        }
    } else {  // MODE 3
        ushort* Co = sl ? C2 : C;
        #pragma unroll
        for (int nt = 0; nt < 4; ++nt) {
            const int n = n0 + wn * 64 + nt * 16 + l16;
            const float bv = sl ? 0.f : bias[n];
            #pragma unroll
            for (int mt = 0; mt < 4; ++mt) {
                #pragma unroll
                for (int r = 0; r < 4; ++r) {
                    const int m = m0 + wm * 64 + mt * 16 + (quad << 2) + r;
                    Co[(size_t)m * N + n] = f2b(acc[mt][nt][r] + bv);
                }
            }
        }
    }
}

// ---------------------------------------------------------------------------
// Flash attention v6: 512 threads (8 waves), Q-tile 128 = 16 q-rows/wave,
// KV-tile 128, single-buffered K/V with split barriers. Per-wave register
// state identical to v4.1 (the round-6 failure doubled per-wave state; this
// doubles WAVES instead): same staging + barriers feed 8 waves, and
// 4 waves/SIMD (vs 2) hide the softmax chains. Ps shrunk to [128 q][64 kv]
// (swz64, verified v3); PV runs in two kv-halves with an own-wave Ps
// rewrite between (same-wave in-order LDS, verified round 6).
// Grid 512 = 2 blocks/CU; LDS 80 KB.
//   QK(t) -> [B] -> issue K(t+1) -> softmax -> P.h0 -> PV.h0 -> P.h1
//   -> PV.h1 -> [C] -> issue V(t+1)
// ---------------------------------------------------------------------------
__global__ __launch_bounds__(512, 4) void attn_kernel(
    ushort* __restrict__ qk, const ushort* __restrict__ vt)
{
    __shared__ __align__(16) ushort smem[40960];
    ushort* Ks = smem;            // [128 kv][128 d], 16-group swizzle
    ushort* Vs = smem + 16384;    // [128 d][128 kv], 16-group swizzle
    ushort* Ps = smem + 32768;    // [128 q][64 kv], swz64

    const int tid  = threadIdx.x;
    const int w    = tid >> 6;        // 0..7
    const int lane = tid & 63;
    const int l16  = lane & 15;
    const int quad = lane >> 4;

    // XCD-aware bijective swizzle: 512 blocks, 8 XCDs (cpx = 64).
    const int bid = ((blockIdx.x & 7) << 6) + (blockIdx.x >> 3);
    const int qb  = bid & 15;          // 16 Q-tiles of 128 rows
    const int h   = (bid >> 4) & 7;
    const int b   = bid >> 7;

    ushort* Qp = qk + ((size_t)(b * SEQ + qb * 128)) * QKS + h * DKH;
    const ushort* Kp = qk + ((size_t)(b * SEQ)) * QKS + 1024 + h * DKH;
    const ushort* Vp = vt + ((size_t)((b * 8 + h) * 128)) * SEQ;

    // ---- prologue: Q (128 rows) -> Vs temp, K(0) -> Ks ----
    #pragma unroll
    for (int i = 0; i < 4; ++i) {
        const int row = w * 16 + i * 4 + quad;
        const int g = (l16 & 8) | ((l16 & 7) ^ (row & 7));
        gl_lds16(Qp + (size_t)row * QKS + g * 8, Vs + (w * 16 + i * 4) * 128);
        gl_lds16(Kp + (size_t)row * QKS + g * 8, Ks + (w * 16 + i * 4) * 128);
    }
    __syncthreads();

    bf16x8 aq[4];
    {
        const int r = w * 16 + l16;
        #pragma unroll
        for (int kq = 0; kq < 4; ++kq) {
            const int gk = kq * 4 + quad;
            const int g = (gk & 8) | ((gk & 7) ^ (r & 7));
            aq[kq] = *(const bf16x8*)&Vs[r * 128 + g * 8];
        }
    }
    __syncthreads();   // Q reads done -> Vs free

    // issue V(0) -> Vs; drains at barrier B of tile 0, before PV(0)
    #pragma unroll
    for (int i = 0; i < 4; ++i) {
        const int d = w * 16 + i * 4 + quad;
        const int g = (l16 & 8) | ((l16 & 7) ^ (d & 7));
        gl_lds16(Vp + (size_t)d * SEQ + g * 8, Vs + (w * 16 + i * 4) * 128);
    }

    f32x4 o[8] = {};
    float mrun[4], lrun[4];
    #pragma unroll
    for (int r = 0; r < 4; ++r) { mrun[r] = -1e30f; lrun[r] = 0.f; }

    const int rowp = w * 16 + l16;          // own-wave Ps read row
    const int roww = w * 16 + (quad << 2);  // own-wave Ps write row base

    for (int t = 0; t < SEQ / 128; ++t) {
        // S' = Q' K^T (Q pre-scaled by 1/sqrt(dk)*log2e at the QKV GEMM)
        f32x4 s[8] = {};
        __builtin_amdgcn_s_setprio(1);
        #pragma unroll
        for (int nt = 0; nt < 8; ++nt) {
            const int rk = nt * 16 + l16;
            #pragma unroll
            for (int kq = 0; kq < 4; ++kq) {
                const int gk = kq * 4 + quad;
                const int g = (gk & 8) | ((gk & 7) ^ (rk & 7));
                bf16x8 bk = *(const bf16x8*)&Ks[rk * 128 + g * 8];
                s[nt] = __builtin_amdgcn_mfma_f32_16x16x32_bf16(aq[kq], bk, s[nt], 0, 0, 0);
            }
        }
        __builtin_amdgcn_s_setprio(0);
        __syncthreads();   // B: Ks reads done everywhere; V(t) staging drained

        // issue K(t+1) -> Ks; flies across softmax + PV, drains at barrier C
        if (t + 1 < SEQ / 128) {
            #pragma unroll
            for (int i = 0; i < 4; ++i) {
                const int row = w * 16 + i * 4 + quad;
                const int g = (l16 & 8) | ((l16 & 7) ^ (row & 7));
                gl_lds16(Kp + ((size_t)((t + 1) * 128 + row)) * QKS + g * 8,
                         Ks + (w * 16 + i * 4) * 128);
            }
        }

        // online softmax (full-tile max), exp2 domain, DPP row-max
        float vmax[4];
        #pragma unroll
        for (int r = 0; r < 4; ++r) {
            float v = s[0][r];
            #pragma unroll
            for (int nt = 1; nt < 8; ++nt) v = fmaxf(v, s[nt][r]);
            vmax[r] = dpp_max16(v);
        }
        const int grew = (vmax[0] > mrun[0]) | (vmax[1] > mrun[1]) |
                         (vmax[2] > mrun[2]) | (vmax[3] > mrun[3]);
        if (__any(grew)) {
            #pragma unroll
            for (int r = 0; r < 4; ++r) {
                const float mnew = fmaxf(mrun[r], vmax[r]);
                const float alpha = exp2_hw(mrun[r] - mnew);
                mrun[r] = mnew;
                lrun[r] *= alpha;
                #pragma unroll
                for (int nt8 = 0; nt8 < 8; ++nt8)
                    o[nt8][r] *= alpha;
            }
        }

        // two kv-halves: P-write (own-wave rows) then PV; Ps reused between
        // halves (same-wave in-order LDS ops make the overwrite safe)
        #pragma unroll
        for (int hh = 0; hh < 2; ++hh) {
            #pragma unroll
            for (int ntl = 0; ntl < 4; ++ntl)
                #pragma unroll
                for (int r = 0; r < 4; ++r) {
                    const float p = exp2_hw(s[hh * 4 + ntl][r] - mrun[r]);
                    lrun[r] += p;
                    const int row = roww + r;
                    Ps[row * 64 + ((ntl * 16 + l16) ^ ((row & 7) << 3))] = f2b_native(p);
                }
            __builtin_amdgcn_s_setprio(1);
            #pragma unroll
            for (int kp = 0; kp < 2; ++kp) {
                const int gpl = kp * 4 + quad;            // 0..7 within half
                bf16x8 ap = *(const bf16x8*)&Ps[rowp * 64 + ((gpl ^ (rowp & 7)) << 3)];
                #pragma unroll
                for (int nt8 = 0; nt8 < 8; ++nt8) {
                    const int d = nt8 * 16 + l16;
                    const int gv = (hh << 3) | (gpl ^ (d & 7));
                    bf16x8 bv = *(const bf16x8*)&Vs[d * 128 + gv * 8];
                    o[nt8] = __builtin_amdgcn_mfma_f32_16x16x32_bf16(ap, bv, o[nt8], 0, 0, 0);
                }
            }
            __builtin_amdgcn_s_setprio(0);
        }

        __syncthreads();   // C: Vs reads done everywhere; K(t+1) staging drained

        // issue V(t+1) -> Vs; flies across next QK, drains at next barrier B
        if (t + 1 < SEQ / 128) {
            #pragma unroll
            for (int i = 0; i < 4; ++i) {
                const int d = w * 16 + i * 4 + quad;
                const int g = (l16 & 8) | ((l16 & 7) ^ (d & 7));
                gl_lds16(Vp + (size_t)d * SEQ + (t + 1) * 128 + g * 8,
                         Vs + (w * 16 + i * 4) * 128);
            }
        }
    }

    // epilogue: finish the deferred l-sum reduce, then write O
    #pragma unroll
    for (int r = 0; r < 4; ++r) {
        float v = lrun[r];
        #pragma unroll
        for (int msk = 1; msk <= 8; msk <<= 1)
            v += __shfl_xor(v, msk, 64);
        lrun[r] = v;
    }
    #pragma unroll
    for (int r = 0; r < 4; ++r) {
        const float inv = 1.f / lrun[r];
        const int row = w * 16 + (quad << 2) + r;
        #pragma unroll
        for (int nt8 = 0; nt8 < 8; ++nt8)
            Qp[(size_t)row * QKS + nt8 * 16 + l16] = f2b_native(o[nt8][r] * inv);
    }
}

// ---------------------------------------------------------------------------
// Residual-add + LayerNorm. a bf16 (stride astride); a2 optional bf16 partial
// (stride 1024); res bf16 or fp32; g/be fp32; out bf16 or fp32.
// ---------------------------------------------------------------------------
__global__ __launch_bounds__(256) void ln_kernel(
    const ushort* __restrict__ a, int astride, const ushort* __restrict__ a2,
    const void* __restrict__ res, int res_f32,
    const float* __restrict__ g, const float* __restrict__ be,
    void* __restrict__ out, int out_f32)
{
    __shared__ float red[8];
    const int row = blockIdx.x;
    const int tid = threadIdx.x;
    const int col = tid * 4;

    ushort av[4];
    *(uint2*)av = *(const uint2*)(a + (size_t)row * astride + col);

    float v[4];
    if (res_f32) {
        float4 rr = *(const float4*)((const float*)res + (size_t)row * D_MODEL + col);
        v[0] = b2f(av[0]) + rr.x; v[1] = b2f(av[1]) + rr.y;
        v[2] = b2f(av[2]) + rr.z; v[3] = b2f(av[3]) + rr.w;
    } else {
        ushort rv[4];
        *(uint2*)rv = *(const uint2*)((const ushort*)res + (size_t)row * D_MODEL + col);
        #pragma unroll
        for (int i = 0; i < 4; ++i) v[i] = b2f(av[i]) + b2f(rv[i]);
    }
    if (a2) {
        ushort bv[4];
        *(uint2*)bv = *(const uint2*)(a2 + (size_t)row * D_MODEL + col);
        #pragma unroll
        for (int i = 0; i < 4; ++i) v[i] += b2f(bv[i]);
    }

    float s = v[0] + v[1] + v[2] + v[3];
    #pragma unroll
    for (int m = 1; m <= 32; m <<= 1) s += __shfl_xor(s, m, 64);
    if ((tid & 63) == 0) red[tid >> 6] = s;
    __syncthreads();
    const float mu = (red[0] + red[1] + red[2] + red[3]) * (1.f / D_MODEL);

    float q = 0.f;
    #pragma unroll
    for (int i = 0; i < 4; ++i) { const float d = v[i] - mu; q += d * d; }
    #pragma unroll
    for (int m = 1; m <= 32; m <<= 1) q += __shfl_xor(q, m, 64);
    if ((tid & 63) == 0) red[4 + (tid >> 6)] = q;
    __syncthreads();
    const float var = (red[4] + red[5] + red[6] + red[7]) * (1.f / D_MODEL);
    const float rstd = rsqrtf(var + 1e-6f);

    float4 gg = *(const float4*)(g + col);
    float4 bb = *(const float4*)(be + col);
    float y[4];
    y[0] = (v[0] - mu) * rstd * gg.x + bb.x;
    y[1] = (v[1] - mu) * rstd * gg.y + bb.y;
    y[2] = (v[2] - mu) * rstd * gg.z + bb.z;
    y[3] = (v[3] - mu) * rstd * gg.w + bb.w;

    if (out_f32) {
        float4 ov; ov.x = y[0]; ov.y = y[1]; ov.z = y[2]; ov.w = y[3];
        *(float4*)((float*)out + (size_t)row * D_MODEL + col) = ov;
    } else {
        ushort ov[4] = { f2b(y[0]), f2b(y[1]), f2b(y[2]), f2b(y[3]) };
        *(uint2*)((ushort*)out + (size_t)row * D_MODEL + col) = *(const uint2*)ov;
    }
}

__global__ __launch_bounds__(256) void sentinel_kernel(float* out, float S, int n) {
    for (int i = blockIdx.x * 256 + threadIdx.x; i < n; i += gridDim.x * 256)
        out[i] = S;
}

// ---------------------------------------------------------------------------
extern "C" void kernel_launch(void* const* d_in, const int* in_sizes, int n_in,
                              void* d_out, int out_size, void* d_ws, size_t ws_size,
                              hipStream_t stream)
{
    const float* x   = (const float*)d_in[0];
    const float* Wq  = (const float*)d_in[1];
    const float* bq  = (const float*)d_in[2];
    const float* Wk  = (const float*)d_in[3];
    const float* bk  = (const float*)d_in[4];
    const float* Wv  = (const float*)d_in[5];
    const float* bv  = (const float*)d_in[6];
    const float* g1  = (const float*)d_in[7];
    const float* be1 = (const float*)d_in[8];
    const float* W1  = (const float*)d_in[9];
    const float* b1  = (const float*)d_in[10];
    const float* W2  = (const float*)d_in[11];
    const float* b2  = (const float*)d_in[12];
    const float* g2  = (const float*)d_in[13];
    const float* be2 = (const float*)d_in[14];

    const size_t MB = 1024 * 1024;
    dim3 blk(256);

    if (ws_size < 88 * MB) {
        int k = (int)(ws_size >> 23); if (k > 127) k = 127;
        sentinel_kernel<<<dim3(2048), blk, 0, stream>>>(
            (float*)d_out, 1024.f + 8.f * (float)k, out_size);
        return;
    }

    // ws layout (88 MB):
    //   0..32M  : qk [8192][2048] bf16 (Q|K; attn-out over Q cols)
    //             -> dead after LN1 -> ffn0 0..16M, ffn1 16..32M
    //   32..48M : vt [32][128][2048] bf16 (V^T per b,h) — dead after attn
    //   48..64M : xb (bf16 x) -> x1 after LN1
    //   64..70M : wqkv_t | 70..78M : w1t | 78..86M : w2t | 86M+: bqkv fp32
    // h-chunk (4096x4096 bf16 = 32 MB) lives in d_out until LN2 overwrites.
    char* ws = (char*)d_ws;
    ushort* qkb    = (ushort*)(ws);
    ushort* vtb    = (ushort*)(ws + 32 * MB);
    ushort* ffn0   = (ushort*)(ws);
    ushort* ffn1   = (ushort*)(ws + 16 * MB);
    ushort* xb     = (ushort*)(ws + 48 * MB);
    ushort* x1     = (ushort*)(ws + 48 * MB);
    ushort* wqkv_t = (ushort*)(ws + 64 * MB);
    ushort* w1t    = (ushort*)(ws + 70 * MB);
    ushort* w2t    = (ushort*)(ws + 78 * MB);
    float*  bqkv   = (float*) (ws + 86 * MB);
    ushort* hbuf   = (ushort*)d_out;

    conv_kernel<<<dim3(2048), blk, 0, stream>>>(x, xb, NTOK * D_MODEL);
    tconv3_kernel<<<dim3(3072), blk, 0, stream>>>(Wq, Wk, Wv, wqkv_t);
    tconv_kernel<<<dim3(4096), blk, 0, stream>>>(W1, w1t, 1024, 4096);
    tconv_kernel<<<dim3(4096), blk, 0, stream>>>(W2, w2t, 4096, 1024);
    cat3_kernel<<<dim3(12), blk, 0, stream>>>(bq, bk, bv, bqkv);

    // fused QKV projection (128x256 deep pipeline): QK -> qkb (Q pre-scaled),
    // V -> vtb transposed. grid 64*12 = 768 = 3 balanced rounds.
    gemm12<2><<<dim3(64 * 12), dim3(512), 0, stream>>>(
        xb, wqkv_t, bqkv, qkb, vtb, NTOK, 3072, D_MODEL);

    attn_kernel<<<dim3(BATCH * NHEADS * (SEQ / 128)), dim3(512), 0, stream>>>(qkb, vtb);

    // x1 = LN(attnO + x)
    ln_kernel<<<dim3(NTOK), blk, 0, stream>>>(qkb, QKS, nullptr, x, 1, g1, be1, x1, 0);

    // FFN in 2 chunks of 4096 rows; h-chunk in d_out.
    // FFN1: 256^2 pipeline (grid 256, 1 round). FFN2: 128x256 pipeline,
    // split-K 2 (grid 2*32*4 = 256, 1 round), partials summed in LN2.
    for (int c = 0; c < 2; ++c) {
        const size_t ro = (size_t)c * 4096;
        gemm8_relu<<<dim3(16 * 16), dim3(512), 0, stream>>>(
            x1 + ro * D_MODEL, w1t, b1, hbuf, 4096, DFF, D_MODEL);
        gemm12<3><<<dim3(2 * 32 * 4), dim3(512), 0, stream>>>(
            hbuf, w2t, b2, ffn0 + ro * D_MODEL, ffn1 + ro * D_MODEL,
            4096, D_MODEL, DFF);
    }

    // out = LN(ffn0 + ffn1 + x1) -> d_out fp32
    ln_kernel<<<dim3(NTOK), blk, 0, stream>>>(ffn0, D_MODEL, ffn1, x1, 0,
                                              g2, be2, d_out, 1);
}

// Round 10
// 498.660 us; speedup vs baseline: 1.1216x; 1.1216x over previous
//
#include <hip/hip_runtime.h>
#include <hip/hip_bf16.h>
#include <stdint.h>

#define D_MODEL 1024
#define NHEADS  8
#define DKH     128
#define DFF     4096
#define SEQ     2048
#define BATCH   4
#define NTOK    (BATCH*SEQ)   // 8192
#define QKS     2048          // row stride of fused QK buffer
// 1/sqrt(128) * log2(e): folded into Q at the QKV GEMM (exp2-domain softmax)
#define QSCALE  0.12751743f

typedef float  f32x4  __attribute__((ext_vector_type(4)));
typedef __bf16 bf16x8 __attribute__((ext_vector_type(8)));

static __device__ __forceinline__ float b2f(ushort u) {
    union { uint32_t i; float f; } v; v.i = ((uint32_t)u) << 16; return v.f;
}
static __device__ __forceinline__ ushort f2b(float f) {
    union { float f; uint32_t i; } v; v.f = f;
    uint32_t r = v.i + 0x7fffu + ((v.i >> 16) & 1u);
    return (ushort)(r >> 16);
}
static __device__ __forceinline__ ushort f2b_native(float f) {
    __bf16 h = (__bf16)f;               // v_cvt (RTNE, same rounding as f2b)
    return __builtin_bit_cast(ushort, h);
}
// hardware 2^x (v_exp_f32)
static __device__ __forceinline__ float exp2_hw(float x) {
    return __builtin_amdgcn_exp2f(x);
}
static __device__ __forceinline__ void gl_lds16(const void* g, void* l) {
    __builtin_amdgcn_global_load_lds(
        (const __attribute__((address_space(1))) void*)g,
        (__attribute__((address_space(3))) void*)l, 16, 0, 0);
}
// butterfly max over each aligned 16-lane group via DPP (no LDS traffic)
static __device__ __forceinline__ float dpp_max16(float x) {
    int t;
    t = __builtin_amdgcn_update_dpp(0, __builtin_bit_cast(int, x), 0xB1, 0xF, 0xF, true);  // quad_perm [1,0,3,2] : xor1
    x = fmaxf(x, __builtin_bit_cast(float, t));
    t = __builtin_amdgcn_update_dpp(0, __builtin_bit_cast(int, x), 0x4E, 0xF, 0xF, true);  // quad_perm [2,3,0,1] : xor2
    x = fmaxf(x, __builtin_bit_cast(float, t));
    t = __builtin_amdgcn_update_dpp(0, __builtin_bit_cast(int, x), 0x141, 0xF, 0xF, true); // row_half_mirror : xor7
    x = fmaxf(x, __builtin_bit_cast(float, t));
    t = __builtin_amdgcn_update_dpp(0, __builtin_bit_cast(int, x), 0x140, 0xF, 0xF, true); // row_mirror : xor15
    x = fmaxf(x, __builtin_bit_cast(float, t));
    return x;
}

// ---------------------------------------------------------------------------
__global__ __launch_bounds__(256) void conv_kernel(
    const float* __restrict__ in, ushort* __restrict__ out, int n)
{
    for (int i = (blockIdx.x * 256 + threadIdx.x) * 4; i < n; i += gridDim.x * 1024) {
        float4 v = *(const float4*)(in + i);
        ushort o[4] = { f2b(v.x), f2b(v.y), f2b(v.z), f2b(v.w) };
        *(uint2*)(out + i) = *(const uint2*)o;
    }
}

// transpose + convert: fp32 [R][C] -> bf16 [C][R]
__global__ __launch_bounds__(256) void tconv_kernel(
    const float* __restrict__ in, ushort* __restrict__ out, int R, int C)
{
    __shared__ float L[32][33];
    const int tid = threadIdx.x;
    const int tx = tid & 31, ty = tid >> 5;
    const int nbc = C >> 5;
    const int r0 = (blockIdx.x / nbc) << 5;
    const int c0 = (blockIdx.x % nbc) << 5;
    #pragma unroll
    for (int p = 0; p < 4; ++p)
        L[ty + 8 * p][tx] = in[(size_t)(r0 + ty + 8 * p) * C + c0 + tx];
    __syncthreads();
    #pragma unroll
    for (int p = 0; p < 4; ++p)
        out[(size_t)(c0 + ty + 8 * p) * R + r0 + tx] = f2b(L[tx][ty + 8 * p]);
}

// fused transpose+convert of Wq|Wk|Wv (each 1024x1024) into wqkv_t
__global__ __launch_bounds__(256) void tconv3_kernel(
    const float* __restrict__ a, const float* __restrict__ b,
    const float* __restrict__ c, ushort* __restrict__ out)
{
    __shared__ float L[32][33];
    const int which = blockIdx.x >> 10;
    const float* in = (which == 0) ? a : (which == 1) ? b : c;
    ushort* o = out + (size_t)which * 1024 * 1024;
    const int bix = blockIdx.x & 1023;
    const int tid = threadIdx.x;
    const int tx = tid & 31, ty = tid >> 5;
    const int r0 = (bix >> 5) << 5;
    const int c0 = (bix & 31) << 5;
    #pragma unroll
    for (int p = 0; p < 4; ++p)
        L[ty + 8 * p][tx] = in[(size_t)(r0 + ty + 8 * p) * 1024 + c0 + tx];
    __syncthreads();
    #pragma unroll
    for (int p = 0; p < 4; ++p)
        o[(size_t)(c0 + ty + 8 * p) * 1024 + r0 + tx] = f2b(L[tx][ty + 8 * p]);
}

__global__ __launch_bounds__(256) void cat3_kernel(
    const float* __restrict__ a, const float* __restrict__ b,
    const float* __restrict__ c, float* __restrict__ out)
{
    const int i = blockIdx.x * 256 + threadIdx.x;
    out[i] = (i < 1024) ? a[i] : (i < 2048) ? b[i - 1024] : c[i - 2048];
}

// ---------------------------------------------------------------------------
// gemm8_relu: 256x256 tile, BK=64, 512 threads (8 waves 2M x 4N), deep
// pipeline with COUNTED vmcnt (T3+T4). C = relu(A @ Bt^T + bias), bf16.
// (verified round 4)
// ---------------------------------------------------------------------------
__global__ __launch_bounds__(512, 2) void gemm8_relu(
    const ushort* __restrict__ A, const ushort* __restrict__ Bt,
    const float* __restrict__ bias, ushort* __restrict__ C,
    int M, int N, int K)
{
    __shared__ __align__(16) ushort lds[65536];   // 128 KB

    const int tid  = threadIdx.x;
    const int w    = tid >> 6;          // 0..7
    const int lane = tid & 63;
    const int l16  = lane & 15;
    const int quad = (lane >> 4) & 3;
    const int wm   = w >> 2;            // 0..1 (M half)
    const int wn   = w & 3;             // 0..3 (N quarter)

    const int nbn = N >> 8;
    const int m0  = (blockIdx.x / nbn) << 8;
    const int n0  = (blockIdx.x % nbn) << 8;

    const int rsub = tid >> 3;                       // 0..63
    const int gsw  = (tid & 7) ^ (rsub & 7);         // pre-swizzled src group
    const ushort* Asrc = A  + (size_t)(m0 + rsub) * K + gsw * 8;
    const ushort* Bsrc = Bt + (size_t)(n0 + rsub) * K + gsw * 8;

    auto issue_half = [&](int p, int kt, int d) {
        const ushort* src;
        int base;
        if (p < 2) { src = Asrc + (size_t)(p * 128) * K;       base = d * 16384 + p * 8192; }
        else       { src = Bsrc + (size_t)((p - 2) * 128) * K; base = 32768 + d * 16384 + (p - 2) * 8192; }
        src += kt * 64;
        gl_lds16(src,                  &lds[base + w * 512]);
        gl_lds16(src + (size_t)64 * K, &lds[base + w * 512 + 4096]);
    };

    f32x4  acc[8][4] = {};
    bf16x8 bfr[4];

    auto phase = [&](int cur, int ks, int mq, bool readB) {
        const int Ab = cur * 16384 + wm * 8192;
        const int Bb = 32768 + cur * 16384 + (wn >> 1) * 8192;
        if (readB) {
            #pragma unroll
            for (int nt = 0; nt < 4; ++nt) {
                const int rB = ((wn & 1) << 6) + nt * 16 + l16;
                const int gB = ((ks << 2) + quad) ^ (rB & 7);
                bfr[nt] = *(const bf16x8*)&lds[Bb + rB * 64 + gB * 8];
            }
        }
        bf16x8 afr[4];
        #pragma unroll
        for (int mt = 0; mt < 4; ++mt) {
            const int rA = mq * 64 + mt * 16 + l16;
            const int gA = ((ks << 2) + quad) ^ (rA & 7);
            afr[mt] = *(const bf16x8*)&lds[Ab + rA * 64 + gA * 8];
        }
        __builtin_amdgcn_s_setprio(1);
        #pragma unroll
        for (int mt = 0; mt < 4; ++mt)
            #pragma unroll
            for (int nt = 0; nt < 4; ++nt)
                acc[mq * 4 + mt][nt] = __builtin_amdgcn_mfma_f32_16x16x32_bf16(
                    afr[mt], bfr[nt], acc[mq * 4 + mt][nt], 0, 0, 0);
        __builtin_amdgcn_s_setprio(0);
    };

    const int NT = K >> 6;

    #pragma unroll
    for (int p = 0; p < 4; ++p) issue_half(p, 0, 0);
    issue_half(0, 1, 1);
    asm volatile("s_waitcnt vmcnt(2)" ::: "memory");
    __builtin_amdgcn_sched_barrier(0);
    __builtin_amdgcn_s_barrier();
    __builtin_amdgcn_sched_barrier(0);

    for (int t = 0; t < NT; ++t) {
        const int  cur = t & 1;
        const bool pf  = (t + 1 < NT);

        if (pf) issue_half(1, t + 1, cur ^ 1);
        phase(cur, 0, 0, true);
        if (pf) issue_half(2, t + 1, cur ^ 1);
        phase(cur, 0, 1, false);
        if (pf) issue_half(3, t + 1, cur ^ 1);
        phase(cur, 1, 0, true);
        phase(cur, 1, 1, false);

        __builtin_amdgcn_sched_barrier(0);
        __builtin_amdgcn_s_barrier();          // A
        __builtin_amdgcn_sched_barrier(0);
        if (pf) {
            if (t + 2 < NT) {
                issue_half(0, t + 2, cur);
                asm volatile("s_waitcnt vmcnt(2)" ::: "memory");
            } else {
                asm volatile("s_waitcnt vmcnt(0)" ::: "memory");
            }
            __builtin_amdgcn_sched_barrier(0);
            __builtin_amdgcn_s_barrier();      // B
            __builtin_amdgcn_sched_barrier(0);
        }
    }
    __builtin_amdgcn_sched_barrier(0);

    #pragma unroll
    for (int nt = 0; nt < 4; ++nt) {
        const int n = n0 + wn * 64 + nt * 16 + l16;
        const float bv = bias[n];
        #pragma unroll
        for (int a = 0; a < 8; ++a) {
            const int mrow = m0 + wm * 128 + (a >> 2) * 64 + (a & 3) * 16 + (quad << 2);
            #pragma unroll
            for (int r = 0; r < 4; ++r) {
                const float v = fmaxf(acc[a][nt][r] + bv, 0.f);
                C[(size_t)(mrow + r) * N + n] = f2b(v);
            }
        }
    }
}

// ---------------------------------------------------------------------------
// gemm12: 128x256 tile, BK=64, 512 threads (8 waves 2M x 4N, wave = 64x64),
// counted-vmcnt deep pipeline, 96 KB LDS. (verified round 5)
// MODE 2: QKV epilogue; MODE 3: split-K 2 slices.
// ---------------------------------------------------------------------------
template<int MODE>
__global__ __launch_bounds__(512, 2) void gemm12(
    const ushort* __restrict__ A, const ushort* __restrict__ Bt,
    const float* __restrict__ bias, ushort* __restrict__ C,
    ushort* __restrict__ C2, int M, int N, int K)
{
    __shared__ __align__(16) ushort lds[49152];   // 96 KB

    const int tid  = threadIdx.x;
    const int w    = tid >> 6;
    const int lane = tid & 63;
    const int l16  = lane & 15;
    const int quad = (lane >> 4) & 3;
    const int wm   = w >> 2;
    const int wn   = w & 3;

    const int cpx  = gridDim.x >> 3;
    const int bidx = (blockIdx.x & 7) * cpx + (blockIdx.x >> 3);

    int tix = bidx, kbeg = 0, kend = K, sl = 0;
    if (MODE == 3) {
        const int tiles = (M >> 7) * (N >> 8);
        sl   = bidx / tiles;
        tix  = bidx % tiles;
        kbeg = sl * (K >> 1);
        kend = kbeg + (K >> 1);
    }
    const int nbn = N >> 8;
    const int m0  = (tix / nbn) << 7;
    const int n0  = (tix % nbn) << 8;

    const int rsub = tid >> 3;
    const int gsw  = (tid & 7) ^ (rsub & 7);
    const ushort* Asrc = A  + (size_t)(m0 + rsub) * K + gsw * 8 + kbeg;
    const ushort* Bsrc = Bt + (size_t)(n0 + rsub) * K + gsw * 8 + kbeg;

    auto issue_half = [&](int p, int kt, int d) {
        const ushort* src;
        int base;
        if (p == 0) { src = Asrc;                              base = d * 8192; }
        else        { src = Bsrc + (size_t)((p - 1) * 128) * K; base = 16384 + d * 16384 + (p - 1) * 8192; }
        src += kt * 64;
        gl_lds16(src,                  &lds[base + w * 512]);
        gl_lds16(src + (size_t)64 * K, &lds[base + w * 512 + 4096]);
    };

    f32x4 acc[4][4] = {};

    auto phase = [&](int cur, int ks) {
        const int Ab = cur * 8192;
        const int Bb = 16384 + cur * 16384;
        bf16x8 afr[4], bfr[4];
        #pragma unroll
        for (int nt = 0; nt < 4; ++nt) {
            const int rB = wn * 64 + nt * 16 + l16;
            const int gB = ((ks << 2) + quad) ^ (rB & 7);
            bfr[nt] = *(const bf16x8*)&lds[Bb + rB * 64 + gB * 8];
        }
        #pragma unroll
        for (int mt = 0; mt < 4; ++mt) {
            const int rA = wm * 64 + mt * 16 + l16;
            const int gA = ((ks << 2) + quad) ^ (rA & 7);
            afr[mt] = *(const bf16x8*)&lds[Ab + rA * 64 + gA * 8];
        }
        __builtin_amdgcn_s_setprio(1);
        #pragma unroll
        for (int mt = 0; mt < 4; ++mt)
            #pragma unroll
            for (int nt = 0; nt < 4; ++nt)
                acc[mt][nt] = __builtin_amdgcn_mfma_f32_16x16x32_bf16(
                    afr[mt], bfr[nt], acc[mt][nt], 0, 0, 0);
        __builtin_amdgcn_s_setprio(0);
    };

    const int NT = (kend - kbeg) >> 6;

    issue_half(0, 0, 0);
    issue_half(1, 0, 0);
    issue_half(2, 0, 0);
    issue_half(0, 1, 1);
    asm volatile("s_waitcnt vmcnt(2)" ::: "memory");
    __builtin_amdgcn_sched_barrier(0);
    __builtin_amdgcn_s_barrier();
    __builtin_amdgcn_sched_barrier(0);

    for (int t = 0; t < NT; ++t) {
        const int  cur = t & 1;
        const bool pf  = (t + 1 < NT);

        if (pf) issue_half(1, t + 1, cur ^ 1);
        phase(cur, 0);
        if (pf) issue_half(2, t + 1, cur ^ 1);
        phase(cur, 1);

        __builtin_amdgcn_sched_barrier(0);
        __builtin_amdgcn_s_barrier();          // A
        __builtin_amdgcn_sched_barrier(0);
        if (pf) {
            if (t + 2 < NT) {
                issue_half(0, t + 2, cur);
                asm volatile("s_waitcnt vmcnt(2)" ::: "memory");
            } else {
                asm volatile("s_waitcnt vmcnt(0)" ::: "memory");
            }
            __builtin_amdgcn_sched_barrier(0);
            __builtin_amdgcn_s_barrier();      // B
            __builtin_amdgcn_sched_barrier(0);
        }
    }
    __builtin_amdgcn_sched_barrier(0);

    if (MODE == 2 && n0 >= 2048) {
        #pragma unroll
        for (int nt = 0; nt < 4; ++nt) {
            const int n  = n0 + wn * 64 + nt * 16 + l16;
            const int hd = n - 2048;
            const float bv = bias[n];
            const size_t vrow = (size_t)(hd >> 7) * 128 + (hd & 127);
            #pragma unroll
            for (int mt = 0; mt < 4; ++mt) {
                const int m = m0 + wm * 64 + mt * 16 + (quad << 2);
                const size_t row = (size_t)(m >> 11) * 1024 + vrow;
                ushort pk[4];
                #pragma unroll
                for (int r = 0; r < 4; ++r) pk[r] = f2b(acc[mt][nt][r] + bv);
                *(uint2*)(C2 + row * SEQ + (m & 2047)) = *(const uint2*)pk;
            }
        }
    } else if (MODE == 2) {
        const float qs = (n0 < 1024) ? QSCALE : 1.f;
        #pragma unroll
        for (int nt = 0; nt < 4; ++nt) {
            const int n = n0 + wn * 64 + nt * 16 + l16;
            const float bv = bias[n];
            #pragma unroll
            for (int mt = 0; mt < 4; ++mt) {
                #pragma unroll
                for (int r = 0; r < 4; ++r) {
                    const int m = m0 + wm * 64 + mt * 16 + (quad << 2) + r;
                    C[(size_t)m * QKS + n] = f2b((acc[mt][nt][r] + bv) * qs);
                }
            }
        }
    } else {  // MODE 3
        ushort* Co = sl ? C2 : C;
        #pragma unroll
        for (int nt = 0; nt < 4; ++nt) {
            const int n = n0 + wn * 64 + nt * 16 + l16;
            const float bv = sl ? 0.f : bias[n];
            #pragma unroll
            for (int mt = 0; mt < 4; ++mt) {
                #pragma unroll
                for (int r = 0; r < 4; ++r) {
                    const int m = m0 + wm * 64 + mt * 16 + (quad << 2) + r;
                    Co[(size_t)m * N + n] = f2b(acc[mt][nt][r] + bv);
                }
            }
        }
    }
}

// ---------------------------------------------------------------------------
// Flash attention v6.1: identical schedule to round-9 v6 (verified correct),
// but __launch_bounds__(512, 2) — round 9's (512,4) capped the unified
// register budget at 128/wave -> 64 arch VGPRs -> scratch spills (FETCH
// 179 MB). With cap 256 the compiler allocates the natural ~116-130 VGPRs
// and hardware occupancy reaches 4 waves/SIMD from actual usage.
// 512 threads (8 waves), Q-tile 128 = 16 q-rows/wave, KV-tile 128,
// single-buffered K/V, split barriers, Ps [128][64] swz64, 2 kv-half PV.
// ---------------------------------------------------------------------------
__global__ __launch_bounds__(512, 2) void attn_kernel(
    ushort* __restrict__ qk, const ushort* __restrict__ vt)
{
    __shared__ __align__(16) ushort smem[40960];
    ushort* Ks = smem;            // [128 kv][128 d], 16-group swizzle
    ushort* Vs = smem + 16384;    // [128 d][128 kv], 16-group swizzle
    ushort* Ps = smem + 32768;    // [128 q][64 kv], swz64

    const int tid  = threadIdx.x;
    const int w    = tid >> 6;        // 0..7
    const int lane = tid & 63;
    const int l16  = lane & 15;
    const int quad = lane >> 4;

    // XCD-aware bijective swizzle: 512 blocks, 8 XCDs (cpx = 64).
    const int bid = ((blockIdx.x & 7) << 6) + (blockIdx.x >> 3);
    const int qb  = bid & 15;          // 16 Q-tiles of 128 rows
    const int h   = (bid >> 4) & 7;
    const int b   = bid >> 7;

    ushort* Qp = qk + ((size_t)(b * SEQ + qb * 128)) * QKS + h * DKH;
    const ushort* Kp = qk + ((size_t)(b * SEQ)) * QKS + 1024 + h * DKH;
    const ushort* Vp = vt + ((size_t)((b * 8 + h) * 128)) * SEQ;

    // ---- prologue: Q (128 rows) -> Vs temp, K(0) -> Ks ----
    #pragma unroll
    for (int i = 0; i < 4; ++i) {
        const int row = w * 16 + i * 4 + quad;
        const int g = (l16 & 8) | ((l16 & 7) ^ (row & 7));
        gl_lds16(Qp + (size_t)row * QKS + g * 8, Vs + (w * 16 + i * 4) * 128);
        gl_lds16(Kp + (size_t)row * QKS + g * 8, Ks + (w * 16 + i * 4) * 128);
    }
    __syncthreads();

    bf16x8 aq[4];
    {
        const int r = w * 16 + l16;
        #pragma unroll
        for (int kq = 0; kq < 4; ++kq) {
            const int gk = kq * 4 + quad;
            const int g = (gk & 8) | ((gk & 7) ^ (r & 7));
            aq[kq] = *(const bf16x8*)&Vs[r * 128 + g * 8];
        }
    }
    __syncthreads();   // Q reads done -> Vs free

    // issue V(0) -> Vs; drains at barrier B of tile 0, before PV(0)
    #pragma unroll
    for (int i = 0; i < 4; ++i) {
        const int d = w * 16 + i * 4 + quad;
        const int g = (l16 & 8) | ((l16 & 7) ^ (d & 7));
        gl_lds16(Vp + (size_t)d * SEQ + g * 8, Vs + (w * 16 + i * 4) * 128);
    }

    f32x4 o[8] = {};
    float mrun[4], lrun[4];
    #pragma unroll
    for (int r = 0; r < 4; ++r) { mrun[r] = -1e30f; lrun[r] = 0.f; }

    const int rowp = w * 16 + l16;          // own-wave Ps read row
    const int roww = w * 16 + (quad << 2);  // own-wave Ps write row base

    for (int t = 0; t < SEQ / 128; ++t) {
        // S' = Q' K^T (Q pre-scaled by 1/sqrt(dk)*log2e at the QKV GEMM)
        f32x4 s[8] = {};
        __builtin_amdgcn_s_setprio(1);
        #pragma unroll
        for (int nt = 0; nt < 8; ++nt) {
            const int rk = nt * 16 + l16;
            #pragma unroll
            for (int kq = 0; kq < 4; ++kq) {
                const int gk = kq * 4 + quad;
                const int g = (gk & 8) | ((gk & 7) ^ (rk & 7));
                bf16x8 bk = *(const bf16x8*)&Ks[rk * 128 + g * 8];
                s[nt] = __builtin_amdgcn_mfma_f32_16x16x32_bf16(aq[kq], bk, s[nt], 0, 0, 0);
            }
        }
        __builtin_amdgcn_s_setprio(0);
        __syncthreads();   // B: Ks reads done everywhere; V(t) staging drained

        // issue K(t+1) -> Ks; flies across softmax + PV, drains at barrier C
        if (t + 1 < SEQ / 128) {
            #pragma unroll
            for (int i = 0; i < 4; ++i) {
                const int row = w * 16 + i * 4 + quad;
                const int g = (l16 & 8) | ((l16 & 7) ^ (row & 7));
                gl_lds16(Kp + ((size_t)((t + 1) * 128 + row)) * QKS + g * 8,
                         Ks + (w * 16 + i * 4) * 128);
            }
        }

        // online softmax (full-tile max), exp2 domain, DPP row-max
        float vmax[4];
        #pragma unroll
        for (int r = 0; r < 4; ++r) {
            float v = s[0][r];
            #pragma unroll
            for (int nt = 1; nt < 8; ++nt) v = fmaxf(v, s[nt][r]);
            vmax[r] = dpp_max16(v);
        }
        const int grew = (vmax[0] > mrun[0]) | (vmax[1] > mrun[1]) |
                         (vmax[2] > mrun[2]) | (vmax[3] > mrun[3]);
        if (__any(grew)) {
            #pragma unroll
            for (int r = 0; r < 4; ++r) {
                const float mnew = fmaxf(mrun[r], vmax[r]);
                const float alpha = exp2_hw(mrun[r] - mnew);
                mrun[r] = mnew;
                lrun[r] *= alpha;
                #pragma unroll
                for (int nt8 = 0; nt8 < 8; ++nt8)
                    o[nt8][r] *= alpha;
            }
        }

        // two kv-halves: P-write (own-wave rows) then PV; Ps reused between
        // halves (same-wave in-order LDS ops make the overwrite safe)
        #pragma unroll
        for (int hh = 0; hh < 2; ++hh) {
            #pragma unroll
            for (int ntl = 0; ntl < 4; ++ntl)
                #pragma unroll
                for (int r = 0; r < 4; ++r) {
                    const float p = exp2_hw(s[hh * 4 + ntl][r] - mrun[r]);
                    lrun[r] += p;
                    const int row = roww + r;
                    Ps[row * 64 + ((ntl * 16 + l16) ^ ((row & 7) << 3))] = f2b_native(p);
                }
            __builtin_amdgcn_s_setprio(1);
            #pragma unroll
            for (int kp = 0; kp < 2; ++kp) {
                const int gpl = kp * 4 + quad;            // 0..7 within half
                bf16x8 ap = *(const bf16x8*)&Ps[rowp * 64 + ((gpl ^ (rowp & 7)) << 3)];
                #pragma unroll
                for (int nt8 = 0; nt8 < 8; ++nt8) {
                    const int d = nt8 * 16 + l16;
                    const int gv = (hh << 3) | (gpl ^ (d & 7));
                    bf16x8 bv = *(const bf16x8*)&Vs[d * 128 + gv * 8];
                    o[nt8] = __builtin_amdgcn_mfma_f32_16x16x32_bf16(ap, bv, o[nt8], 0, 0, 0);
                }
            }
            __builtin_amdgcn_s_setprio(0);
        }

        __syncthreads();   // C: Vs reads done everywhere; K(t+1) staging drained

        // issue V(t+1) -> Vs; flies across next QK, drains at next barrier B
        if (t + 1 < SEQ / 128) {
            #pragma unroll
            for (int i = 0; i < 4; ++i) {
                const int d = w * 16 + i * 4 + quad;
                const int g = (l16 & 8) | ((l16 & 7) ^ (d & 7));
                gl_lds16(Vp + (size_t)d * SEQ + (t + 1) * 128 + g * 8,
                         Vs + (w * 16 + i * 4) * 128);
            }
        }
    }

    // epilogue: finish the deferred l-sum reduce, then write O
    #pragma unroll
    for (int r = 0; r < 4; ++r) {
        float v = lrun[r];
        #pragma unroll
        for (int msk = 1; msk <= 8; msk <<= 1)
            v += __shfl_xor(v, msk, 64);
        lrun[r] = v;
    }
    #pragma unroll
    for (int r = 0; r < 4; ++r) {
        const float inv = 1.f / lrun[r];
        const int row = w * 16 + (quad << 2) + r;
        #pragma unroll
        for (int nt8 = 0; nt8 < 8; ++nt8)
            Qp[(size_t)row * QKS + nt8 * 16 + l16] = f2b_native(o[nt8][r] * inv);
    }
}

// ---------------------------------------------------------------------------
// Residual-add + LayerNorm. a bf16 (stride astride); a2 optional bf16 partial
// (stride 1024); res bf16 or fp32; g/be fp32; out bf16 or fp32.
// ---------------------------------------------------------------------------
__global__ __launch_bounds__(256) void ln_kernel(
    const ushort* __restrict__ a, int astride, const ushort* __restrict__ a2,
    const void* __restrict__ res, int res_f32,
    const float* __restrict__ g, const float* __restrict__ be,
    void* __restrict__ out, int out_f32)
{
    __shared__ float red[8];
    const int row = blockIdx.x;
    const int tid = threadIdx.x;
    const int col = tid * 4;

    ushort av[4];
    *(uint2*)av = *(const uint2*)(a + (size_t)row * astride + col);

    float v[4];
    if (res_f32) {
        float4 rr = *(const float4*)((const float*)res + (size_t)row * D_MODEL + col);
        v[0] = b2f(av[0]) + rr.x; v[1] = b2f(av[1]) + rr.y;
        v[2] = b2f(av[2]) + rr.z; v[3] = b2f(av[3]) + rr.w;
    } else {
        ushort rv[4];
        *(uint2*)rv = *(const uint2*)((const ushort*)res + (size_t)row * D_MODEL + col);
        #pragma unroll
        for (int i = 0; i < 4; ++i) v[i] = b2f(av[i]) + b2f(rv[i]);
    }
    if (a2) {
        ushort bv[4];
        *(uint2*)bv = *(const uint2*)(a2 + (size_t)row * D_MODEL + col);
        #pragma unroll
        for (int i = 0; i < 4; ++i) v[i] += b2f(bv[i]);
    }

    float s = v[0] + v[1] + v[2] + v[3];
    #pragma unroll
    for (int m = 1; m <= 32; m <<= 1) s += __shfl_xor(s, m, 64);
    if ((tid & 63) == 0) red[tid >> 6] = s;
    __syncthreads();
    const float mu = (red[0] + red[1] + red[2] + red[3]) * (1.f / D_MODEL);

    float q = 0.f;
    #pragma unroll
    for (int i = 0; i < 4; ++i) { const float d = v[i] - mu; q += d * d; }
    #pragma unroll
    for (int m = 1; m <= 32; m <<= 1) q += __shfl_xor(q, m, 64);
    if ((tid & 63) == 0) red[4 + (tid >> 6)] = q;
    __syncthreads();
    const float var = (red[4] + red[5] + red[6] + red[7]) * (1.f / D_MODEL);
    const float rstd = rsqrtf(var + 1e-6f);

    float4 gg = *(const float4*)(g + col);
    float4 bb = *(const float4*)(be + col);
    float y[4];
    y[0] = (v[0] - mu) * rstd * gg.x + bb.x;
    y[1] = (v[1] - mu) * rstd * gg.y + bb.y;
    y[2] = (v[2] - mu) * rstd * gg.z + bb.z;
    y[3] = (v[3] - mu) * rstd * gg.w + bb.w;

    if (out_f32) {
        float4 ov; ov.x = y[0]; ov.y = y[1]; ov.z = y[2]; ov.w = y[3];
        *(float4*)((float*)out + (size_t)row * D_MODEL + col) = ov;
    } else {
        ushort ov[4] = { f2b(y[0]), f2b(y[1]), f2b(y[2]), f2b(y[3]) };
        *(uint2*)((ushort*)out + (size_t)row * D_MODEL + col) = *(const uint2*)ov;
    }
}

__global__ __launch_bounds__(256) void sentinel_kernel(float* out, float S, int n) {
    for (int i = blockIdx.x * 256 + threadIdx.x; i < n; i += gridDim.x * 256)
        out[i] = S;
}

// ---------------------------------------------------------------------------
extern "C" void kernel_launch(void* const* d_in, const int* in_sizes, int n_in,
                              void* d_out, int out_size, void* d_ws, size_t ws_size,
                              hipStream_t stream)
{
    const float* x   = (const float*)d_in[0];
    const float* Wq  = (const float*)d_in[1];
    const float* bq  = (const float*)d_in[2];
    const float* Wk  = (const float*)d_in[3];
    const float* bk  = (const float*)d_in[4];
    const float* Wv  = (const float*)d_in[5];
    const float* bv  = (const float*)d_in[6];
    const float* g1  = (const float*)d_in[7];
    const float* be1 = (const float*)d_in[8];
    const float* W1  = (const float*)d_in[9];
    const float* b1  = (const float*)d_in[10];
    const float* W2  = (const float*)d_in[11];
    const float* b2  = (const float*)d_in[12];
    const float* g2  = (const float*)d_in[13];
    const float* be2 = (const float*)d_in[14];

    const size_t MB = 1024 * 1024;
    dim3 blk(256);

    if (ws_size < 88 * MB) {
        int k = (int)(ws_size >> 23); if (k > 127) k = 127;
        sentinel_kernel<<<dim3(2048), blk, 0, stream>>>(
            (float*)d_out, 1024.f + 8.f * (float)k, out_size);
        return;
    }

    // ws layout (88 MB):
    //   0..32M  : qk [8192][2048] bf16 (Q|K; attn-out over Q cols)
    //             -> dead after LN1 -> ffn0 0..16M, ffn1 16..32M
    //   32..48M : vt [32][128][2048] bf16 (V^T per b,h) — dead after attn
    //   48..64M : xb (bf16 x) -> x1 after LN1
    //   64..70M : wqkv_t | 70..78M : w1t | 78..86M : w2t | 86M+: bqkv fp32
    // h-chunk (4096x4096 bf16 = 32 MB) lives in d_out until LN2 overwrites.
    char* ws = (char*)d_ws;
    ushort* qkb    = (ushort*)(ws);
    ushort* vtb    = (ushort*)(ws + 32 * MB);
    ushort* ffn0   = (ushort*)(ws);
    ushort* ffn1   = (ushort*)(ws + 16 * MB);
    ushort* xb     = (ushort*)(ws + 48 * MB);
    ushort* x1     = (ushort*)(ws + 48 * MB);
    ushort* wqkv_t = (ushort*)(ws + 64 * MB);
    ushort* w1t    = (ushort*)(ws + 70 * MB);
    ushort* w2t    = (ushort*)(ws + 78 * MB);
    float*  bqkv   = (float*) (ws + 86 * MB);
    ushort* hbuf   = (ushort*)d_out;

    conv_kernel<<<dim3(2048), blk, 0, stream>>>(x, xb, NTOK * D_MODEL);
    tconv3_kernel<<<dim3(3072), blk, 0, stream>>>(Wq, Wk, Wv, wqkv_t);
    tconv_kernel<<<dim3(4096), blk, 0, stream>>>(W1, w1t, 1024, 4096);
    tconv_kernel<<<dim3(4096), blk, 0, stream>>>(W2, w2t, 4096, 1024);
    cat3_kernel<<<dim3(12), blk, 0, stream>>>(bq, bk, bv, bqkv);

    // fused QKV projection (128x256 deep pipeline): QK -> qkb (Q pre-scaled),
    // V -> vtb transposed. grid 64*12 = 768 = 3 balanced rounds.
    gemm12<2><<<dim3(64 * 12), dim3(512), 0, stream>>>(
        xb, wqkv_t, bqkv, qkb, vtb, NTOK, 3072, D_MODEL);

    attn_kernel<<<dim3(BATCH * NHEADS * (SEQ / 128)), dim3(512), 0, stream>>>(qkb, vtb);

    // x1 = LN(attnO + x)
    ln_kernel<<<dim3(NTOK), blk, 0, stream>>>(qkb, QKS, nullptr, x, 1, g1, be1, x1, 0);

    // FFN in 2 chunks of 4096 rows; h-chunk in d_out.
    // FFN1: 256^2 pipeline (grid 256, 1 round). FFN2: 128x256 pipeline,
    // split-K 2 (grid 2*32*4 = 256, 1 round), partials summed in LN2.
    for (int c = 0; c < 2; ++c) {
        const size_t ro = (size_t)c * 4096;
        gemm8_relu<<<dim3(16 * 16), dim3(512), 0, stream>>>(
            x1 + ro * D_MODEL, w1t, b1, hbuf, 4096, DFF, D_MODEL);
        gemm12<3><<<dim3(2 * 32 * 4), dim3(512), 0, stream>>>(
            hbuf, w2t, b2, ffn0 + ro * D_MODEL, ffn1 + ro * D_MODEL,
            4096, D_MODEL, DFF);
    }

    // out = LN(ffn0 + ffn1 + x1) -> d_out fp32
    ln_kernel<<<dim3(NTOK), blk, 0, stream>>>(ffn0, D_MODEL, ffn1, x1, 0,
                                              g2, be2, d_out, 1);
}